// Round 1
// baseline (1163.072 us; speedup 1.0000x reference)
//
#include <hip/hip_runtime.h>

#define NN 50000
#define NC 256
#define DD 64
#define HH 128
#define EVV 800000
#define EVC 400000

// Y[r] = relu(X[r] @ W1 + b1) @ W2 + b2  for 16 rows per block.
// block = 256 threads = 4 waves; each wave handles 4 rows (register-blocked
// so each W1/W2 global load feeds 4 FMAs). grid*16 must equal nrows.
// W1 is [64][128] row-major, W2 is [128][64] row-major.
__global__ __launch_bounds__(256) void mlp_rows(
    const float* __restrict__ X, const float* __restrict__ W1,
    const float* __restrict__ b1, const float* __restrict__ W2,
    const float* __restrict__ b2, float* __restrict__ Y) {
  const int wave = threadIdx.x >> 6;
  const int lane = threadIdx.x & 63;
  const int row0 = (blockIdx.x * 4 + wave) * 4;

  __shared__ float xs[4][4][64];    // [wave][row][k]
  __shared__ float hs[4][4][128];   // [wave][row][j]

#pragma unroll
  for (int r = 0; r < 4; ++r)
    xs[wave][r][lane] = X[(row0 + r) * DD + lane];
  __syncthreads();

  // phase 1: hidden = relu(x @ W1 + b1); lane owns hidden units {lane, lane+64}
  const float bias0 = b1[lane];
  const float bias1 = b1[lane + 64];
  float h0[4], h1[4];
#pragma unroll
  for (int r = 0; r < 4; ++r) { h0[r] = bias0; h1[r] = bias1; }

#pragma unroll 16
  for (int k = 0; k < 64; ++k) {
    const float wa = W1[k * HH + lane];        // coalesced, L1-resident
    const float wb = W1[k * HH + 64 + lane];
#pragma unroll
    for (int r = 0; r < 4; ++r) {
      const float xv = xs[wave][r][k];         // LDS broadcast (free)
      h0[r] = fmaf(xv, wa, h0[r]);
      h1[r] = fmaf(xv, wb, h1[r]);
    }
  }
#pragma unroll
  for (int r = 0; r < 4; ++r) {
    hs[wave][r][lane] = fmaxf(h0[r], 0.0f);
    hs[wave][r][lane + 64] = fmaxf(h1[r], 0.0f);
  }
  __syncthreads();

  // phase 2: out = hidden @ W2 + b2; lane owns output unit {lane}
  const float bias2 = b2[lane];
  float acc[4];
#pragma unroll
  for (int r = 0; r < 4; ++r) acc[r] = bias2;

#pragma unroll 16
  for (int j = 0; j < HH; ++j) {
    const float w = W2[j * DD + lane];         // coalesced, L1-resident
#pragma unroll
    for (int r = 0; r < 4; ++r)
      acc[r] = fmaf(hs[wave][r][j], w, acc[r]);
  }
#pragma unroll
  for (int r = 0; r < 4; ++r)
    Y[(row0 + r) * DD + lane] = acc[r];
}

// For each edge e: out[dst[e]][:] += M[src[e]][:]   (64 floats/row)
// 16 threads per edge, one float4 gather + 4 fp32 global atomics per thread.
__global__ __launch_bounds__(256) void scatter_add(
    const float4* __restrict__ M, const int* __restrict__ src,
    const int* __restrict__ dst, float* __restrict__ out, int nedges) {
  const int t = blockIdx.x * 256 + threadIdx.x;
  const int e = t >> 4;
  const int c = t & 15;
  if (e >= nedges) return;
  const int s = src[e];
  const int d = dst[e];
  const float4 v = M[s * 16 + c];
  float* o = out + d * DD + c * 4;
  atomicAdd(o + 0, v.x);
  atomicAdd(o + 1, v.y);
  atomicAdd(o + 2, v.z);
  atomicAdd(o + 3, v.w);
}

__global__ __launch_bounds__(256) void relu_inplace(float4* __restrict__ out,
                                                    int n4) {
  const int t = blockIdx.x * 256 + threadIdx.x;
  if (t >= n4) return;
  float4 v = out[t];
  v.x = fmaxf(v.x, 0.0f);
  v.y = fmaxf(v.y, 0.0f);
  v.z = fmaxf(v.z, 0.0f);
  v.w = fmaxf(v.w, 0.0f);
  out[t] = v;
}

extern "C" void kernel_launch(void* const* d_in, const int* in_sizes, int n_in,
                              void* d_out, int out_size, void* d_ws,
                              size_t ws_size, hipStream_t stream) {
  const float* x_v = (const float*)d_in[0];
  const float* x_c = (const float*)d_in[1];
  const float* W1v = (const float*)d_in[2];
  const float* b1v = (const float*)d_in[3];
  const float* W2v = (const float*)d_in[4];
  const float* b2v = (const float*)d_in[5];
  const float* W1c = (const float*)d_in[6];
  const float* b1c = (const float*)d_in[7];
  const float* W2c = (const float*)d_in[8];
  const float* b2c = (const float*)d_in[9];
  const int* src_vv = (const int*)d_in[10];
  const int* dst_vv = (const int*)d_in[11];
  const int* src_vc = (const int*)d_in[12];
  const int* dst_vc = (const int*)d_in[13];
  float* out = (float*)d_out;

  float* mv = (float*)d_ws;          // [NN][DD] = 12.8 MB
  float* mc = mv + (size_t)NN * DD;  // [NC][DD] = 64 KB

  // out := x_v  (accumulator init)
  hipMemcpyAsync(out, x_v, (size_t)NN * DD * sizeof(float),
                 hipMemcpyDeviceToDevice, stream);

  // precompute per-node / per-color messages (MLP commutes with gather)
  mlp_rows<<<NN / 16, 256, 0, stream>>>(x_v, W1v, b1v, W2v, b2v, mv);
  mlp_rows<<<NC / 16, 256, 0, stream>>>(x_c, W1c, b1c, W2c, b2c, mc);

  // scatter-sum messages into out
  scatter_add<<<(EVV * 16) / 256, 256, 0, stream>>>((const float4*)mv, src_vv,
                                                    dst_vv, out, EVV);
  scatter_add<<<(EVC * 16) / 256, 256, 0, stream>>>((const float4*)mc, src_vc,
                                                    dst_vc, out, EVC);

  // out := relu(out)
  relu_inplace<<<(NN * DD / 4) / 256, 256, 0, stream>>>((float4*)out,
                                                        NN * DD / 4);
}

// Round 2
// 346.658 us; speedup vs baseline: 3.3551x; 3.3551x over previous
//
#include <hip/hip_runtime.h>

#define NN 50000
#define NC 256
#define DD 64
#define HH 128
#define EVV 800000
#define EVC 400000
#define NE (EVV + EVC)

// ---------------------------------------------------------------------------
// MLP: Y[r] = relu(X[r] @ W1 + b1) @ W2 + b2 for 16 rows per block.
// block = 256 = 4 waves; each wave handles 4 rows register-blocked.
// ---------------------------------------------------------------------------
__global__ __launch_bounds__(256) void mlp_rows(
    const float* __restrict__ X, const float* __restrict__ W1,
    const float* __restrict__ b1, const float* __restrict__ W2,
    const float* __restrict__ b2, float* __restrict__ Y) {
  const int wave = threadIdx.x >> 6;
  const int lane = threadIdx.x & 63;
  const int row0 = (blockIdx.x * 4 + wave) * 4;

  __shared__ float xs[4][4][64];
  __shared__ float hs[4][4][128];

#pragma unroll
  for (int r = 0; r < 4; ++r)
    xs[wave][r][lane] = X[(row0 + r) * DD + lane];
  __syncthreads();

  const float bias0 = b1[lane];
  const float bias1 = b1[lane + 64];
  float h0[4], h1[4];
#pragma unroll
  for (int r = 0; r < 4; ++r) { h0[r] = bias0; h1[r] = bias1; }

#pragma unroll 16
  for (int k = 0; k < 64; ++k) {
    const float wa = W1[k * HH + lane];
    const float wb = W1[k * HH + 64 + lane];
#pragma unroll
    for (int r = 0; r < 4; ++r) {
      const float xv = xs[wave][r][k];
      h0[r] = fmaf(xv, wa, h0[r]);
      h1[r] = fmaf(xv, wb, h1[r]);
    }
  }
#pragma unroll
  for (int r = 0; r < 4; ++r) {
    hs[wave][r][lane] = fmaxf(h0[r], 0.0f);
    hs[wave][r][lane + 64] = fmaxf(h1[r], 0.0f);
  }
  __syncthreads();

  const float bias2 = b2[lane];
  float acc[4];
#pragma unroll
  for (int r = 0; r < 4; ++r) acc[r] = bias2;

#pragma unroll 16
  for (int j = 0; j < HH; ++j) {
    const float w = W2[j * DD + lane];
#pragma unroll
    for (int r = 0; r < 4; ++r)
      acc[r] = fmaf(hs[wave][r][j], w, acc[r]);
  }
#pragma unroll
  for (int r = 0; r < 4; ++r)
    Y[(row0 + r) * DD + lane] = acc[r];
}

// ---------------------------------------------------------------------------
// CSR build step 1: histogram of in-degrees (int atomics, 50K bins -> low
// contention).
// ---------------------------------------------------------------------------
__global__ __launch_bounds__(256) void hist_kernel(
    const int* __restrict__ dst, int* __restrict__ deg, int nedges) {
  const int e = blockIdx.x * 256 + threadIdx.x;
  if (e >= nedges) return;
  atomicAdd(&deg[dst[e]], 1);
}

// ---------------------------------------------------------------------------
// CSR build step 2: exclusive scan, single block of 1024 threads, shfl-based
// wave scans (no per-step __syncthreads). n = NN+1; in has NN entries, out
// gets NN+1 (out[NN] = total).
// ---------------------------------------------------------------------------
__global__ __launch_bounds__(1024) void exscan_kernel(
    const int* __restrict__ in, int* __restrict__ out, int n_in, int n_out) {
  __shared__ int wsum[16];
  __shared__ int carry_s;
  const int lane = threadIdx.x & 63;
  const int wid = threadIdx.x >> 6;
  if (threadIdx.x == 0) carry_s = 0;
  __syncthreads();

  for (int base = 0; base < n_out; base += 1024) {
    const int i = base + threadIdx.x;
    const int v = (i < n_in) ? in[i] : 0;
    // inclusive wave scan
    int x = v;
#pragma unroll
    for (int o = 1; o < 64; o <<= 1) {
      int t = __shfl_up(x, o, 64);
      if (lane >= o) x += t;
    }
    if (lane == 63) wsum[wid] = x;
    __syncthreads();                       // wsum visible
    const int carry = carry_s;             // everyone reads old carry
    __syncthreads();                       // before wave 0 updates it
    if (wid == 0 && lane < 16) {
      const int w = wsum[lane];
      int y = w;
#pragma unroll
      for (int o = 1; o < 16; o <<= 1) {
        int t = __shfl_up(y, o, 16);
        if ((lane & 15) >= o) y += t;
      }
      wsum[lane] = y - w;                  // exclusive wave offset
      if (lane == 15) carry_s = carry + y; // new running total
    }
    __syncthreads();                       // wsum/carry updated
    if (i < n_out) out[i] = carry + wsum[wid] + (x - v);
    __syncthreads();                       // protect wsum reuse
  }
}

// ---------------------------------------------------------------------------
// CSR build step 3: bucket fill. idx[off[d] + cursor[d]++] = base + src.
// ---------------------------------------------------------------------------
__global__ __launch_bounds__(256) void fill_kernel(
    const int* __restrict__ src, const int* __restrict__ dst,
    const int* __restrict__ off, int* __restrict__ cur, int* __restrict__ idx,
    int nedges, int base) {
  const int e = blockIdx.x * 256 + threadIdx.x;
  if (e >= nedges) return;
  const int d = dst[e];
  const int pos = off[d] + atomicAdd(&cur[d], 1);
  idx[pos] = base + src[e];
}

// ---------------------------------------------------------------------------
// Gather: out[v] = relu(x_v[v] + sum_{j in CSR row v} table[idx[j]]).
// One wave per vertex: lane = sub*16 + c; 4 edges in flight; c = float4 chunk.
// ---------------------------------------------------------------------------
__global__ __launch_bounds__(256) void gather_kernel(
    const float4* __restrict__ table, const int* __restrict__ off,
    const int* __restrict__ idx, const float4* __restrict__ xv,
    float4* __restrict__ out, int nv) {
  const int wave = threadIdx.x >> 6;
  const int lane = threadIdx.x & 63;
  const int v = blockIdx.x * 4 + wave;
  if (v >= nv) return;
  const int c = lane & 15;
  const int sub = lane >> 4;

  const int s0 = off[v];
  const int s1 = off[v + 1];

  float ax = 0.0f, ay = 0.0f, az = 0.0f, aw = 0.0f;
  for (int j = s0 + sub; j < s1; j += 4) {
    const int s = idx[j];                 // broadcast within 16-lane group
    const float4 t = table[s * 16 + c];   // 256 B coalesced per group
    ax += t.x; ay += t.y; az += t.z; aw += t.w;
  }
  // reduce the 4 sub-accumulators (xor 16, 32)
  ax += __shfl_xor(ax, 16); ay += __shfl_xor(ay, 16);
  az += __shfl_xor(az, 16); aw += __shfl_xor(aw, 16);
  ax += __shfl_xor(ax, 32); ay += __shfl_xor(ay, 32);
  az += __shfl_xor(az, 32); aw += __shfl_xor(aw, 32);

  if (sub == 0) {
    const float4 x = xv[(size_t)v * 16 + c];
    float4 r;
    r.x = fmaxf(x.x + ax, 0.0f);
    r.y = fmaxf(x.y + ay, 0.0f);
    r.z = fmaxf(x.z + az, 0.0f);
    r.w = fmaxf(x.w + aw, 0.0f);
    out[(size_t)v * 16 + c] = r;
  }
}

extern "C" void kernel_launch(void* const* d_in, const int* in_sizes, int n_in,
                              void* d_out, int out_size, void* d_ws,
                              size_t ws_size, hipStream_t stream) {
  const float* x_v = (const float*)d_in[0];
  const float* x_c = (const float*)d_in[1];
  const float* W1v = (const float*)d_in[2];
  const float* b1v = (const float*)d_in[3];
  const float* W2v = (const float*)d_in[4];
  const float* b2v = (const float*)d_in[5];
  const float* W1c = (const float*)d_in[6];
  const float* b1c = (const float*)d_in[7];
  const float* W2c = (const float*)d_in[8];
  const float* b2c = (const float*)d_in[9];
  const int* src_vv = (const int*)d_in[10];
  const int* dst_vv = (const int*)d_in[11];
  const int* src_vc = (const int*)d_in[12];
  const int* dst_vc = (const int*)d_in[13];
  float* out = (float*)d_out;

  // workspace layout (all 16B aligned)
  char* p = (char*)d_ws;
  float* table = (float*)p;                 // [NN+NC][64] = 12.87 MB
  p += (size_t)(NN + NC) * DD * sizeof(float);
  int* deg = (int*)p; p += ((size_t)NN + 4) * sizeof(int);
  int* off = (int*)p; p += ((size_t)NN + 4) * sizeof(int);
  int* cur = (int*)p; p += ((size_t)NN + 4) * sizeof(int);
  int* idx = (int*)p;                       // [NE] = 4.8 MB

  // zero the histogram + cursors (ws is poisoned 0xAA before every call)
  hipMemsetAsync(deg, 0, (size_t)NN * sizeof(int), stream);
  hipMemsetAsync(cur, 0, (size_t)NN * sizeof(int), stream);

  // per-node / per-color messages (MLP commutes with the gather)
  mlp_rows<<<NN / 16, 256, 0, stream>>>(x_v, W1v, b1v, W2v, b2v, table);
  mlp_rows<<<NC / 16, 256, 0, stream>>>(x_c, W1c, b1c, W2c, b2c,
                                        table + (size_t)NN * DD);

  // CSR over the union of both edge lists (color srcs offset by NN)
  hist_kernel<<<(EVV + 255) / 256, 256, 0, stream>>>(dst_vv, deg, EVV);
  hist_kernel<<<(EVC + 255) / 256, 256, 0, stream>>>(dst_vc, deg, EVC);
  exscan_kernel<<<1, 1024, 0, stream>>>(deg, off, NN, NN + 1);
  fill_kernel<<<(EVV + 255) / 256, 256, 0, stream>>>(src_vv, dst_vv, off, cur,
                                                     idx, EVV, 0);
  fill_kernel<<<(EVC + 255) / 256, 256, 0, stream>>>(src_vc, dst_vc, off, cur,
                                                     idx, EVC, NN);

  // fused gather + x_v add + relu
  gather_kernel<<<(NN + 3) / 4, 256, 0, stream>>>(
      (const float4*)table, off, idx, (const float4*)x_v, (float4*)out, NN);
}

// Round 3
// 227.504 us; speedup vs baseline: 5.1123x; 1.5237x over previous
//
#include <hip/hip_runtime.h>

#define NN 50000
#define NC 256
#define DD 64
#define HH 128
#define EVV 800000
#define EVC 400000
#define NE (EVV + EVC)

#define MLPV_B 3125              // NN/16
#define MLPC_B 16                // NC/16
#define HV_B 3125                // EVV/256
#define HC_B 1563                // ceil(EVC/256)
#define K1_B (MLPV_B + MLPC_B + HV_B + HC_B)
#define SB 49                    // ceil((NN+1)/1024) scan blocks

// ---------------------------------------------------------------------------
// MLP for 16 rows: Y[r] = relu(X[r]@W1 + b1)@W2 + b2.
// 4 waves/block, 4 rows/wave. Transposed LDS layouts so the per-iteration
// LDS traffic is ONE broadcast ds_read_b128 (all 4 rows at once).
// ---------------------------------------------------------------------------
__device__ __forceinline__ void mlp16(
    const float* __restrict__ X, const float* __restrict__ W1,
    const float* __restrict__ b1, const float* __restrict__ W2,
    const float* __restrict__ b2, float* __restrict__ Y, int blk,
    float (*xs)[64][4], float (*hs)[128][4]) {
  const int wave = threadIdx.x >> 6;
  const int lane = threadIdx.x & 63;
  const int row0 = (blk * 4 + wave) * 4;

  // stage x transposed: xs[k][r] = X[row0+r][k]; lane = k
  {
    float4 xw;
    xw.x = X[(row0 + 0) * DD + lane];
    xw.y = X[(row0 + 1) * DD + lane];
    xw.z = X[(row0 + 2) * DD + lane];
    xw.w = X[(row0 + 3) * DD + lane];
    *(float4*)&xs[wave][lane][0] = xw;
  }
  __syncthreads();

  // phase 1: lane owns hidden units {lane, lane+64}
  const float bias0 = b1[lane];
  const float bias1 = b1[lane + 64];
  float h0x = bias0, h0y = bias0, h0z = bias0, h0w = bias0;
  float h1x = bias1, h1y = bias1, h1z = bias1, h1w = bias1;

  const float4* xv4 = (const float4*)&xs[wave][0][0];
#pragma unroll 8
  for (int k = 0; k < 64; ++k) {
    const float4 xk = xv4[k];                  // 16B LDS broadcast
    const float wa = W1[k * HH + lane];        // coalesced, L1-hot
    const float wb = W1[k * HH + 64 + lane];
    h0x = fmaf(xk.x, wa, h0x); h1x = fmaf(xk.x, wb, h1x);
    h0y = fmaf(xk.y, wa, h0y); h1y = fmaf(xk.y, wb, h1y);
    h0z = fmaf(xk.z, wa, h0z); h1z = fmaf(xk.z, wb, h1z);
    h0w = fmaf(xk.w, wa, h0w); h1w = fmaf(xk.w, wb, h1w);
  }
  *(float4*)&hs[wave][lane][0] =
      make_float4(fmaxf(h0x, 0.f), fmaxf(h0y, 0.f), fmaxf(h0z, 0.f),
                  fmaxf(h0w, 0.f));
  *(float4*)&hs[wave][lane + 64][0] =
      make_float4(fmaxf(h1x, 0.f), fmaxf(h1y, 0.f), fmaxf(h1z, 0.f),
                  fmaxf(h1w, 0.f));
  __syncthreads();

  // phase 2: lane owns output unit {lane}
  const float bias2 = b2[lane];
  float ax = bias2, ay = bias2, az = bias2, aw = bias2;
  const float4* hv4 = (const float4*)&hs[wave][0][0];
#pragma unroll 8
  for (int j = 0; j < HH; ++j) {
    const float4 hj = hv4[j];                  // 16B LDS broadcast
    const float w = W2[j * DD + lane];         // coalesced, L1-hot
    ax = fmaf(hj.x, w, ax);
    ay = fmaf(hj.y, w, ay);
    az = fmaf(hj.z, w, az);
    aw = fmaf(hj.w, w, aw);
  }
  Y[(row0 + 0) * DD + lane] = ax;
  Y[(row0 + 1) * DD + lane] = ay;
  Y[(row0 + 2) * DD + lane] = az;
  Y[(row0 + 3) * DD + lane] = aw;
}

// ---------------------------------------------------------------------------
// K1 fused: MLP_v | MLP_c | hist_vv | hist_vc by block range. Hist stores the
// atomicAdd return as the edge's rank (kills round-2's second atomic pass).
// VALU-bound MLP blocks co-schedule with latency-bound hist blocks (m114).
// ---------------------------------------------------------------------------
__global__ __launch_bounds__(256) void k1_kernel(
    const float* __restrict__ x_v, const float* __restrict__ x_c,
    const float* __restrict__ W1v, const float* __restrict__ b1v,
    const float* __restrict__ W2v, const float* __restrict__ b2v,
    const float* __restrict__ W1c, const float* __restrict__ b1c,
    const float* __restrict__ W2c, const float* __restrict__ b2c,
    const int* __restrict__ dst_vv, const int* __restrict__ dst_vc,
    float* __restrict__ table, int* __restrict__ deg, int* __restrict__ rank) {
  __shared__ float xs[4][64][4];
  __shared__ float hs[4][128][4];
  const int b = blockIdx.x;
  if (b < MLPV_B) {
    mlp16(x_v, W1v, b1v, W2v, b2v, table, b, xs, hs);
  } else if (b < MLPV_B + MLPC_B) {
    mlp16(x_c, W1c, b1c, W2c, b2c, table + (size_t)NN * DD, b - MLPV_B, xs, hs);
  } else if (b < MLPV_B + MLPC_B + HV_B) {
    const int e = (b - MLPV_B - MLPC_B) * 256 + threadIdx.x;  // always < EVV
    rank[e] = atomicAdd(&deg[dst_vv[e]], 1);
  } else {
    const int e = (b - MLPV_B - MLPC_B - HV_B) * 256 + threadIdx.x;
    if (e < EVC) rank[EVV + e] = atomicAdd(&deg[dst_vc[e]], 1);
  }
}

// ---------------------------------------------------------------------------
// Two-level exclusive scan of deg[NN] -> off[NN+1]. 1024 items/block.
// ---------------------------------------------------------------------------
__global__ __launch_bounds__(256) void scan1_kernel(const int* __restrict__ deg,
                                                    int* __restrict__ bsum) {
  const int lane = threadIdx.x & 63;
  const int wid = threadIdx.x >> 6;
  const int base = blockIdx.x * 1024 + threadIdx.x * 4;
  int s = 0;
#pragma unroll
  for (int r = 0; r < 4; ++r) {
    const int i = base + r;
    if (i < NN) s += deg[i];
  }
#pragma unroll
  for (int o = 32; o > 0; o >>= 1) s += __shfl_down(s, o, 64);
  __shared__ int ws[4];
  if (lane == 0) ws[wid] = s;
  __syncthreads();
  if (threadIdx.x == 0) bsum[blockIdx.x] = ws[0] + ws[1] + ws[2] + ws[3];
}

__global__ __launch_bounds__(64) void scan2_kernel(const int* __restrict__ bsum,
                                                   int* __restrict__ boff) {
  const int t = threadIdx.x;
  const int v = (t < SB) ? bsum[t] : 0;
  int x = v;
#pragma unroll
  for (int o = 1; o < 64; o <<= 1) {
    int u = __shfl_up(x, o, 64);
    if (t >= o) x += u;
  }
  if (t < SB) boff[t] = x - v;
}

__global__ __launch_bounds__(256) void scan3_kernel(const int* __restrict__ deg,
                                                    const int* __restrict__ boff,
                                                    int* __restrict__ off) {
  const int lane = threadIdx.x & 63;
  const int wid = threadIdx.x >> 6;
  const int base = blockIdx.x * 1024 + threadIdx.x * 4;
  int v[4], t = 0;
#pragma unroll
  for (int r = 0; r < 4; ++r) {
    const int i = base + r;
    v[r] = (i < NN) ? deg[i] : 0;
    t += v[r];
  }
  int x = t;
#pragma unroll
  for (int o = 1; o < 64; o <<= 1) {
    int u = __shfl_up(x, o, 64);
    if (lane >= o) x += u;
  }
  __shared__ int wsum[4];
  if (lane == 63) wsum[wid] = x;
  __syncthreads();
  int wpre = 0;
  for (int w = 0; w < wid; ++w) wpre += wsum[w];
  int run = boff[blockIdx.x] + wpre + (x - t);  // exclusive before this thread
#pragma unroll
  for (int r = 0; r < 4; ++r) {
    const int i = base + r;
    if (i <= NN) off[i] = run;
    run += v[r];
  }
}

// ---------------------------------------------------------------------------
// Bucket fill, atomic-free: idx[off[d] + rank[e]] = src(+base).
// ---------------------------------------------------------------------------
__global__ __launch_bounds__(256) void fill_kernel(
    const int* __restrict__ src_vv, const int* __restrict__ dst_vv,
    const int* __restrict__ src_vc, const int* __restrict__ dst_vc,
    const int* __restrict__ off, const int* __restrict__ rank,
    int* __restrict__ idx) {
  const int e = blockIdx.x * 256 + threadIdx.x;
  if (e >= NE) return;
  int s, d;
  if (e < EVV) {
    d = dst_vv[e];
    s = src_vv[e];
  } else {
    d = dst_vc[e - EVV];
    s = NN + src_vc[e - EVV];
  }
  idx[off[d] + rank[e]] = s;
}

// ---------------------------------------------------------------------------
// Gather: out[v] = relu(x_v[v] + sum_{j in row v} table[idx[j]]).
// One wave/vertex, 4 edges in flight, 16 lanes per edge (256B coalesced).
// ---------------------------------------------------------------------------
__global__ __launch_bounds__(256) void gather_kernel(
    const float4* __restrict__ table, const int* __restrict__ off,
    const int* __restrict__ idx, const float4* __restrict__ xv,
    float4* __restrict__ out) {
  const int wave = threadIdx.x >> 6;
  const int lane = threadIdx.x & 63;
  const int v = blockIdx.x * 4 + wave;
  if (v >= NN) return;
  const int c = lane & 15;
  const int sub = lane >> 4;

  const int s0 = off[v];
  const int s1 = off[v + 1];

  float ax = 0.f, ay = 0.f, az = 0.f, aw = 0.f;
  for (int j = s0 + sub; j < s1; j += 4) {
    const int s = idx[j];
    const float4 t = table[(size_t)s * 16 + c];
    ax += t.x; ay += t.y; az += t.z; aw += t.w;
  }
  ax += __shfl_xor(ax, 16); ay += __shfl_xor(ay, 16);
  az += __shfl_xor(az, 16); aw += __shfl_xor(aw, 16);
  ax += __shfl_xor(ax, 32); ay += __shfl_xor(ay, 32);
  az += __shfl_xor(az, 32); aw += __shfl_xor(aw, 32);

  if (sub == 0) {
    const float4 x = xv[(size_t)v * 16 + c];
    float4 r;
    r.x = fmaxf(x.x + ax, 0.f);
    r.y = fmaxf(x.y + ay, 0.f);
    r.z = fmaxf(x.z + az, 0.f);
    r.w = fmaxf(x.w + aw, 0.f);
    out[(size_t)v * 16 + c] = r;
  }
}

extern "C" void kernel_launch(void* const* d_in, const int* in_sizes, int n_in,
                              void* d_out, int out_size, void* d_ws,
                              size_t ws_size, hipStream_t stream) {
  const float* x_v = (const float*)d_in[0];
  const float* x_c = (const float*)d_in[1];
  const float* W1v = (const float*)d_in[2];
  const float* b1v = (const float*)d_in[3];
  const float* W2v = (const float*)d_in[4];
  const float* b2v = (const float*)d_in[5];
  const float* W1c = (const float*)d_in[6];
  const float* b1c = (const float*)d_in[7];
  const float* W2c = (const float*)d_in[8];
  const float* b2c = (const float*)d_in[9];
  const int* src_vv = (const int*)d_in[10];
  const int* dst_vv = (const int*)d_in[11];
  const int* src_vc = (const int*)d_in[12];
  const int* dst_vc = (const int*)d_in[13];
  float* out = (float*)d_out;

  // workspace layout (16B-aligned slabs)
  char* p = (char*)d_ws;
  float* table = (float*)p;                  // [NN+NC][64] = 12.87 MB
  p += (size_t)(NN + NC) * DD * sizeof(float);
  int* deg = (int*)p;  p += ((size_t)NN + 16) * sizeof(int);
  int* off = (int*)p;  p += ((size_t)NN + 16) * sizeof(int);
  int* bsum = (int*)p; p += 64 * sizeof(int);
  int* boff = (int*)p; p += 64 * sizeof(int);
  int* rank = (int*)p; p += (size_t)NE * sizeof(int);   // 4.8 MB
  int* idx = (int*)p;                                   // 4.8 MB

  hipMemsetAsync(deg, 0, (size_t)NN * sizeof(int), stream);

  // fused MLP(v) + MLP(c) + histogram/rank (both edge lists)
  k1_kernel<<<K1_B, 256, 0, stream>>>(x_v, x_c, W1v, b1v, W2v, b2v, W1c, b1c,
                                      W2c, b2c, dst_vv, dst_vc, table, deg,
                                      rank);

  // two-level exclusive scan: deg -> off
  scan1_kernel<<<SB, 256, 0, stream>>>(deg, bsum);
  scan2_kernel<<<1, 64, 0, stream>>>(bsum, boff);
  scan3_kernel<<<SB, 256, 0, stream>>>(deg, boff, off);

  // atomic-free bucket fill (both lists in one dispatch)
  fill_kernel<<<(NE + 255) / 256, 256, 0, stream>>>(src_vv, dst_vv, src_vc,
                                                    dst_vc, off, rank, idx);

  // fused gather + x_v add + relu
  gather_kernel<<<(NN + 3) / 4, 256, 0, stream>>>(
      (const float4*)table, off, idx, (const float4*)x_v, (float4*)out);
}